// Round 10
// baseline (124.245 us; speedup 1.0000x reference)
//
#include <hip/hip_runtime.h>

// Bahdanau additive attention: B=8, TE=512, TD=256, H=256, fp32.
//   We = enc @ W_a; Uh = dec @ U_a
//   e[b,j,i] = softmax_i( sum_h V[h]*tanh(We[b,i,h]+Uh[b,j,h]) )
//   c[b,j,h] = sum_i e[b,j,i]*enc[b,i,h]
// d_out = [c (B*TD*H)] ++ [e (B*TD*TE)]
//
// Identity (R3): tanh(x) = 1 - 2/(1+exp2(Kx)); exp2(K(w+u)) = w~*u~ in the
// exp2 domain -> v_rcp is the only transcendental.
// R8: 4-way reciprocal batching (14 full-rate + 1 rcp per 4 elements).
// R10: occupancy fix — 2 j per 512-thread block, grid 1024 -> 4 blocks/CU
// (LDS 20 KB, VGPR<=64 via (512,8)) = 8 waves/SIMD; Uhe j-pair-interleaved
// so one uniform dwordx4 feeds both j at 2 h. Phase A unroll 4.
// Keeps: XCD swizzle (b=blockIdx&7), interleaved W4 layout.
// R5 lesson: no (1024,8) bounds (spill). R9 lesson: pk fp32 adds no rate.

#define BB 8
#define TE 512
#define TD 256
#define HH 256

#define EXP2F(x) __builtin_amdgcn_exp2f(x)
#define RCPF(x)  __builtin_amdgcn_rcpf(x)
#define KSCALE   2.8853900817779268f    // 2*log2(e)
#define NSC      (-2.8853900817779268f) // -2*log2(e)

typedef float v2f __attribute__((ext_vector_type(2)));

// ---------------------------------------------------------------------------
// k_pre: C = [enc;dec] @ [Wa|Ua]; store exp2(KSCALE*C).
// Blocks 0..255: enc -> W4[b][h/4][i][4] (interleaved-transposed).
// Blocks 256..383: dec -> Uhe2[j/2][h][2] (j-pair-interleaved).
// 64x64 tile, Kc=32, 4x4 per thread (tx=col-quad, ty=row-quad).
// ---------------------------------------------------------------------------
__global__ __launch_bounds__(256) void k_pre(
    const float* __restrict__ enc, const float* __restrict__ dec,
    const float* __restrict__ Wa,  const float* __restrict__ Ua,
    float* __restrict__ W4, float* __restrict__ Uhe2)
{
    const int tid = threadIdx.x;
    const bool is_enc = blockIdx.x < 256;
    const int bi = is_enc ? blockIdx.x : (blockIdx.x - 256);
    const int m0 = (bi >> 2) * 64;
    const int n0 = (bi & 3) * 64;
    const float* X = is_enc ? enc : dec;
    const float* W = is_enc ? Wa : Ua;

    __shared__ float Xs[32][68];
    __shared__ float Ws[32][68];

    const int kq = tid & 7,  xr = tid >> 3;
    const int wk = tid >> 3, wn = (tid & 7) * 8;
    const int tx = tid & 15, ty = tid >> 4;

    float acc[4][4];   // acc[r = row-offset][c = col-offset]
    #pragma unroll
    for (int r = 0; r < 4; r++)
        #pragma unroll
        for (int c = 0; c < 4; c++) acc[r][c] = 0.f;

    for (int kc = 0; kc < HH; kc += 32) {
        float4 xa = *(const float4*)(X + (size_t)(m0 + xr) * HH + kc + kq * 4);
        float4 xb = *(const float4*)(X + (size_t)(m0 + xr + 32) * HH + kc + kq * 4);
        float4 wa = *(const float4*)(W + (size_t)(kc + wk) * HH + n0 + wn);
        float4 wb = *(const float4*)(W + (size_t)(kc + wk) * HH + n0 + wn + 4);
        __syncthreads();
        Xs[kq * 4 + 0][xr] = xa.x; Xs[kq * 4 + 1][xr] = xa.y;
        Xs[kq * 4 + 2][xr] = xa.z; Xs[kq * 4 + 3][xr] = xa.w;
        Xs[kq * 4 + 0][xr + 32] = xb.x; Xs[kq * 4 + 1][xr + 32] = xb.y;
        Xs[kq * 4 + 2][xr + 32] = xb.z; Xs[kq * 4 + 3][xr + 32] = xb.w;
        *(float4*)&Ws[wk][wn]     = wa;
        *(float4*)&Ws[wk][wn + 4] = wb;
        __syncthreads();
        #pragma unroll
        for (int k = 0; k < 32; k++) {
            float4 a = *(const float4*)&Xs[k][ty * 4];   // 4 rows
            float4 b = *(const float4*)&Ws[k][tx * 4];   // 4 cols
            acc[0][0] = fmaf(a.x, b.x, acc[0][0]); acc[0][1] = fmaf(a.x, b.y, acc[0][1]);
            acc[0][2] = fmaf(a.x, b.z, acc[0][2]); acc[0][3] = fmaf(a.x, b.w, acc[0][3]);
            acc[1][0] = fmaf(a.y, b.x, acc[1][0]); acc[1][1] = fmaf(a.y, b.y, acc[1][1]);
            acc[1][2] = fmaf(a.y, b.z, acc[1][2]); acc[1][3] = fmaf(a.y, b.w, acc[1][3]);
            acc[2][0] = fmaf(a.z, b.x, acc[2][0]); acc[2][1] = fmaf(a.z, b.y, acc[2][1]);
            acc[2][2] = fmaf(a.z, b.z, acc[2][2]); acc[2][3] = fmaf(a.z, b.w, acc[2][3]);
            acc[3][0] = fmaf(a.w, b.x, acc[3][0]); acc[3][1] = fmaf(a.w, b.y, acc[3][1]);
            acc[3][2] = fmaf(a.w, b.z, acc[3][2]); acc[3][3] = fmaf(a.w, b.w, acc[3][3]);
        }
    }

    if (is_enc) {
        const int b  = m0 >> 9;                  // 512 enc rows per batch
        const int ib = (m0 & 511) + ty * 4;      // i base
        const int hq = (n0 >> 2) + tx;           // h-quad
        float* dst = W4 + (((size_t)b * 64 + hq) * TE + ib) * 4;
        #pragma unroll
        for (int r = 0; r < 4; r++) {
            float4 v;
            v.x = EXP2F(acc[r][0] * KSCALE); v.y = EXP2F(acc[r][1] * KSCALE);
            v.z = EXP2F(acc[r][2] * KSCALE); v.w = EXP2F(acc[r][3] * KSCALE);
            *(float4*)(dst + (size_t)r * 4) = v;
        }
    } else {
        // j-pair-interleaved: Uhe2[(jj>>1)*HH + col][jj&1]
        #pragma unroll
        for (int r = 0; r < 4; r++) {
            const int j = m0 + ty * 4 + r;
            float* dst = Uhe2 + ((size_t)(j >> 1) * HH + n0 + tx * 4) * 2 + (j & 1);
            dst[0] = EXP2F(acc[r][0] * KSCALE);
            dst[2] = EXP2F(acc[r][1] * KSCALE);
            dst[4] = EXP2F(acc[r][2] * KSCALE);
            dst[6] = EXP2F(acc[r][3] * KSCALE);
        }
    }
}

// ---------------------------------------------------------------------------
// k_attn: 512 threads = 8 waves; block owns 2 consecutive j's of ONE batch,
// batch = blockIdx&7 (XCD-local). Grid 1024 -> 4 blocks/CU, 8 waves/SIMD.
// Phase A: wave w -> i = 64w+lane, 64 h-quads; per quad one b128 W4 load
// (lane-varying) + 2 uniform dwordx4 u loads + uniform va; 4-way batched
// reciprocal packed over the j-pair (2 rcp / 8 elems). Softmax: waves 0-1.
// Phase B: wave w -> i in [64w,64w+64), both j; 16 KB LDS reduce.
// ---------------------------------------------------------------------------
__global__ __launch_bounds__(512, 8) void k_attn(
    const float* __restrict__ enc, const float* __restrict__ W4,
    const float* __restrict__ Uhe2, const float* __restrict__ Va,
    float* __restrict__ out_c, float* __restrict__ out_e)
{
    const int wv = threadIdx.x >> 6, lane = threadIdx.x & 63;
    const int b   = blockIdx.x & 7;           // XCD-local batch
    const int j0  = (blockIdx.x >> 3) * 2;    // 128 j-pairs per batch
    const int jj0 = b * TD + j0;              // block-uniform

    __shared__ float sP[TE][2];      // 4 KB: energies -> probabilities
    __shared__ float sR[8][2][HH];   // 16 KB: phase-B partials

    const int i = (wv << 6) + lane;
    const float* wp = W4 + ((size_t)b * 64 * TE + i) * 4;
    const float4* up = (const float4*)(Uhe2 + (size_t)(jj0 >> 1) * HH * 2);
    const float4* vp = (const float4*)Va;

    v2f acc = {0.f, 0.f};
    const v2f one = {1.f, 1.f};

    #pragma unroll 4
    for (int q = 0; q < 64; q++) {
        float4 w4 = *(const float4*)(wp + (size_t)q * TE * 4);
        float4 v4  = vp[q];            // uniform
        float4 u01 = up[2 * q];        // uniform: {u(h0,j0),u(h0,j1),u(h1,j0),u(h1,j1)}
        float4 u23 = up[2 * q + 1];    // h2, h3
        v2f uA; uA.x = u01.x; uA.y = u01.y;
        v2f uB; uB.x = u01.z; uB.y = u01.w;
        v2f uC; uC.x = u23.x; uC.y = u23.y;
        v2f uD; uD.x = u23.z; uD.y = u23.w;
        v2f A = __builtin_elementwise_fma((v2f)(w4.x), uA, one);
        v2f B = __builtin_elementwise_fma((v2f)(w4.y), uB, one);
        v2f C = __builtin_elementwise_fma((v2f)(w4.z), uC, one);
        v2f D = __builtin_elementwise_fma((v2f)(w4.w), uD, one);
        v2f dAB = A * B, dCD = C * D;
        v2f nAB = __builtin_elementwise_fma((v2f)(v4.x), B, (v2f)(v4.y) * A);
        v2f nCD = __builtin_elementwise_fma((v2f)(v4.z), D, (v2f)(v4.w) * C);
        v2f num = __builtin_elementwise_fma(nAB, dCD, nCD * dAB);
        v2f den = dAB * dCD;
        v2f r; r.x = RCPF(den.x); r.y = RCPF(den.y);
        acc = __builtin_elementwise_fma(num, r, acc);
    }

    // energies (log2 domain), j-pair row per i
    float2 E; E.x = NSC * acc.x; E.y = NSC * acc.y;
    *(float2*)&sP[i][0] = E;
    __syncthreads();

    // ---- softmax: wave 0 -> j0, wave 1 -> j0+1 ---------------------------
    if (wv < 2) {
        float ev[8];
        float m = -3.0e38f;
        #pragma unroll
        for (int k = 0; k < 8; k++) {
            ev[k] = sP[lane + 64 * k][wv];
            m = fmaxf(m, ev[k]);
        }
        #pragma unroll
        for (int off = 32; off; off >>= 1) m = fmaxf(m, __shfl_xor(m, off, 64));
        float s = 0.f;
        #pragma unroll
        for (int k = 0; k < 8; k++) { ev[k] = EXP2F(ev[k] - m); s += ev[k]; }
        #pragma unroll
        for (int off = 32; off; off >>= 1) s += __shfl_xor(s, off, 64);
        float rs = RCPF(s);
        float* oe = out_e + (size_t)(jj0 + wv) * TE;
        #pragma unroll
        for (int k = 0; k < 8; k++) {
            float p = ev[k] * rs;
            sP[lane + 64 * k][wv] = p;
            oe[lane + 64 * k] = p;
        }
    }
    __syncthreads();

    // ---- Phase B: wave w -> i in [64w, 64w+64), both j -------------------
    const int ib = wv << 6;
    const float* eb = enc + ((size_t)b * TE + ib) * HH + 4 * lane;
    v2f cx = {0,0}, cy = {0,0}, cz = {0,0}, cw = {0,0};
    #pragma unroll 2
    for (int k = 0; k < 64; k++) {
        float2 pr = *(const float2*)&sP[ib + k][0];   // uniform broadcast
        v2f p; p.x = pr.x; p.y = pr.y;
        float4 q = *(const float4*)(eb + (size_t)k * HH);
        cx = __builtin_elementwise_fma(p, (v2f)(q.x), cx);
        cy = __builtin_elementwise_fma(p, (v2f)(q.y), cy);
        cz = __builtin_elementwise_fma(p, (v2f)(q.z), cz);
        cw = __builtin_elementwise_fma(p, (v2f)(q.w), cw);
    }
    {
        float4 c0; c0.x = cx.x; c0.y = cy.x; c0.z = cz.x; c0.w = cw.x;
        float4 c1; c1.x = cx.y; c1.y = cy.y; c1.z = cz.y; c1.w = cw.y;
        *(float4*)&sR[wv][0][4 * lane] = c0;
        *(float4*)&sR[wv][1][4 * lane] = c1;
    }
    __syncthreads();

    // ---- final reduce: wave w -> (j = w&1, h-quarter = w>>1) -------------
    {
        const int jr = wv & 1;
        const int h  = (wv >> 1) * 64 + lane;
        float s = 0.f;
        #pragma unroll
        for (int ww = 0; ww < 8; ww++) s += sR[ww][jr][h];
        out_c[(size_t)(jj0 + jr) * HH + h] = s;
    }
}

extern "C" void kernel_launch(void* const* d_in, const int* in_sizes, int n_in,
                              void* d_out, int out_size, void* d_ws, size_t ws_size,
                              hipStream_t stream) {
    const float* enc = (const float*)d_in[0];
    const float* dec = (const float*)d_in[1];
    const float* Wa  = (const float*)d_in[2];
    const float* Ua  = (const float*)d_in[3];
    const float* Va  = (const float*)d_in[4];

    float* W4   = (float*)d_ws;                      // exp2-domain, i-interleaved
    float* Uhe2 = W4 + (size_t)BB * HH * TE;         // exp2-domain, j-pair-interleaved

    float* out_c = (float*)d_out;                    // [B,TD,H]
    float* out_e = out_c + (size_t)BB * TD * HH;     // [B,TD,TE]

    k_pre<<<384, 256, 0, stream>>>(enc, dec, Wa, Ua, W4, Uhe2);
    k_attn<<<BB * TD / 2, 512, 0, stream>>>(enc, W4, Uhe2, Va, out_c, out_e);
}

// Round 11
// 114.874 us; speedup vs baseline: 1.0816x; 1.0816x over previous
//
#include <hip/hip_runtime.h>

// Bahdanau additive attention: B=8, TE=512, TD=256, H=256, fp32.
//   We = enc @ W_a; Uh = dec @ U_a
//   e[b,j,i] = softmax_i( sum_h V[h]*tanh(We[b,i,h]+Uh[b,j,h]) )
//   c[b,j,h] = sum_i e[b,j,i]*enc[b,i,h]
// d_out = [c (B*TD*H)] ++ [e (B*TD*TE)]
//
// Identity (R3): tanh(x) = 1 - 2/(1+exp2(Kx)); exp2(K(w+u)) = w~*u~ in the
// exp2 domain -> v_rcp is the only transcendental.
// R11: L1-bandwidth fix. Evidence: VALU busy-time ~21us constant across R7-R10
// while stalls ~19us are invariant to occupancy (R10: 2x waves, no change) ->
// shared-pipe saturation: phase A's 1KB b128 per 144 VALU-cyc per wave at 16
// waves/CU = ~113 B/cyc vs ~128 B/cyc L1 return width. Fix: fp16 operand
// cache (W4h, enc16) halves bytes; one b128 now feeds 8 h. Math stays fp32
// (fp16 products would overflow: den up to 2^52). 8-way rcp batching:
// 30 full-rate + 1 rcp per 8 elements.
// Keeps: R8 shape (4 j/block, 4 independent chains, grid 512), XCD swizzle.
// R5 lesson: no (1024,8) bounds (spill). R9/R10 lesson: pk fp32 no gain,
// j-packing kills ILP.

#define BB 8
#define TE 512
#define TD 256
#define HH 256

#define EXP2F(x) __builtin_amdgcn_exp2f(x)
#define RCPF(x)  __builtin_amdgcn_rcpf(x)
#define KSCALE   2.8853900817779268f    // 2*log2(e)
#define NSC      (-2.8853900817779268f) // -2*log2(e)

typedef _Float16 h4 __attribute__((ext_vector_type(4)));
typedef _Float16 h8 __attribute__((ext_vector_type(8)));

// ---------------------------------------------------------------------------
// k_pre: blocks 0..255: We = enc@Wa -> W4h[b][h/8][i][8] fp16, exp2-domain.
//        blocks 256..383: Uh = dec@Ua -> Uhe[j][h] fp32, exp2-domain.
//        blocks 384..447: enc -> enc16 fp16 copy (phase-B operand).
// GEMM: 64x64 tile, Kc=32, 4x4 per thread (tx=col-quad, ty=row-quad).
// ---------------------------------------------------------------------------
__global__ __launch_bounds__(256) void k_pre(
    const float* __restrict__ enc, const float* __restrict__ dec,
    const float* __restrict__ Wa,  const float* __restrict__ Ua,
    _Float16* __restrict__ W4h, float* __restrict__ Uhe,
    _Float16* __restrict__ enc16)
{
    const int tid = threadIdx.x;

    if (blockIdx.x >= 384) {               // enc -> fp16 copy, coalesced
        const size_t base = (size_t)(blockIdx.x - 384) * 16384;
        #pragma unroll 4
        for (int t = 0; t < 16; t++) {
            size_t idx = base + ((size_t)t * 256 + tid) * 4;
            float4 v = *(const float4*)(enc + idx);
            h4 o; o.x = (_Float16)v.x; o.y = (_Float16)v.y;
            o.z = (_Float16)v.z; o.w = (_Float16)v.w;
            *(h4*)(enc16 + idx) = o;
        }
        return;
    }

    const bool is_enc = blockIdx.x < 256;
    const int bi = is_enc ? blockIdx.x : (blockIdx.x - 256);
    const int m0 = (bi >> 2) * 64;
    const int n0 = (bi & 3) * 64;
    const float* X = is_enc ? enc : dec;
    const float* W = is_enc ? Wa : Ua;

    __shared__ float Xs[32][68];
    __shared__ float Ws[32][68];

    const int kq = tid & 7,  xr = tid >> 3;
    const int wk = tid >> 3, wn = (tid & 7) * 8;
    const int tx = tid & 15, ty = tid >> 4;

    float acc[4][4];   // acc[r = row-offset][c = col-offset]
    #pragma unroll
    for (int r = 0; r < 4; r++)
        #pragma unroll
        for (int c = 0; c < 4; c++) acc[r][c] = 0.f;

    for (int kc = 0; kc < HH; kc += 32) {
        float4 xa = *(const float4*)(X + (size_t)(m0 + xr) * HH + kc + kq * 4);
        float4 xb = *(const float4*)(X + (size_t)(m0 + xr + 32) * HH + kc + kq * 4);
        float4 wa = *(const float4*)(W + (size_t)(kc + wk) * HH + n0 + wn);
        float4 wb = *(const float4*)(W + (size_t)(kc + wk) * HH + n0 + wn + 4);
        __syncthreads();
        Xs[kq * 4 + 0][xr] = xa.x; Xs[kq * 4 + 1][xr] = xa.y;
        Xs[kq * 4 + 2][xr] = xa.z; Xs[kq * 4 + 3][xr] = xa.w;
        Xs[kq * 4 + 0][xr + 32] = xb.x; Xs[kq * 4 + 1][xr + 32] = xb.y;
        Xs[kq * 4 + 2][xr + 32] = xb.z; Xs[kq * 4 + 3][xr + 32] = xb.w;
        *(float4*)&Ws[wk][wn]     = wa;
        *(float4*)&Ws[wk][wn + 4] = wb;
        __syncthreads();
        #pragma unroll
        for (int k = 0; k < 32; k++) {
            float4 a = *(const float4*)&Xs[k][ty * 4];   // 4 rows
            float4 b = *(const float4*)&Ws[k][tx * 4];   // 4 cols
            acc[0][0] = fmaf(a.x, b.x, acc[0][0]); acc[0][1] = fmaf(a.x, b.y, acc[0][1]);
            acc[0][2] = fmaf(a.x, b.z, acc[0][2]); acc[0][3] = fmaf(a.x, b.w, acc[0][3]);
            acc[1][0] = fmaf(a.y, b.x, acc[1][0]); acc[1][1] = fmaf(a.y, b.y, acc[1][1]);
            acc[1][2] = fmaf(a.y, b.z, acc[1][2]); acc[1][3] = fmaf(a.y, b.w, acc[1][3]);
            acc[2][0] = fmaf(a.z, b.x, acc[2][0]); acc[2][1] = fmaf(a.z, b.y, acc[2][1]);
            acc[2][2] = fmaf(a.z, b.z, acc[2][2]); acc[2][3] = fmaf(a.z, b.w, acc[2][3]);
            acc[3][0] = fmaf(a.w, b.x, acc[3][0]); acc[3][1] = fmaf(a.w, b.y, acc[3][1]);
            acc[3][2] = fmaf(a.w, b.z, acc[3][2]); acc[3][3] = fmaf(a.w, b.w, acc[3][3]);
        }
    }

    if (is_enc) {
        const int b  = m0 >> 9;                   // batch
        const int ib = (m0 & 511) + ty * 4;       // i base
        const int hh = n0 + tx * 4;               // h base (4 contiguous)
        const int o  = hh >> 3;                   // h-octet
        const int hf = (hh & 7);                  // 0 or 4 within octet
        #pragma unroll
        for (int r = 0; r < 4; r++) {
            h4 v;
            v.x = (_Float16)EXP2F(acc[r][0] * KSCALE);
            v.y = (_Float16)EXP2F(acc[r][1] * KSCALE);
            v.z = (_Float16)EXP2F(acc[r][2] * KSCALE);
            v.w = (_Float16)EXP2F(acc[r][3] * KSCALE);
            *(h4*)(W4h + (((size_t)b * 32 + o) * TE + ib + r) * 8 + hf) = v;
        }
    } else {
        #pragma unroll
        for (int r = 0; r < 4; r++) {
            float4 v;
            v.x = EXP2F(acc[r][0] * KSCALE); v.y = EXP2F(acc[r][1] * KSCALE);
            v.z = EXP2F(acc[r][2] * KSCALE); v.w = EXP2F(acc[r][3] * KSCALE);
            *(float4*)(Uhe + (size_t)(m0 + ty * 4 + r) * HH + n0 + tx * 4) = v;
        }
    }
}

// ---------------------------------------------------------------------------
// k_attn: 512 threads = 8 waves; block owns 4 consecutive j's of ONE batch,
// batch = blockIdx&7 (XCD-local). Phase A: wave w -> i = 64w+lane, 32 h-octets;
// per octet: ONE b128 fp16 W load (8 h) + uniform u/va s_loads; per j:
// 8-way batched reciprocal (30 full-rate + 1 rcp per 8 elems), 4 independent
// j-chains. Softmax: waves 0-3. Phase B: fp16 enc16, 4 j; 32 KB LDS reduce.
// ---------------------------------------------------------------------------
__global__ __launch_bounds__(512) void k_attn(
    const _Float16* __restrict__ enc16, const _Float16* __restrict__ W4h,
    const float* __restrict__ Uhe, const float* __restrict__ Va,
    float* __restrict__ out_c, float* __restrict__ out_e)
{
    const int wv = threadIdx.x >> 6, lane = threadIdx.x & 63;
    const int b   = blockIdx.x & 7;           // XCD-local batch
    const int j0  = (blockIdx.x >> 3) * 4;    // 64 j-groups per batch
    const int jj0 = b * TD + j0;              // block-uniform

    __shared__ float sP[4][TE];      // 8 KB: energies -> probabilities
    __shared__ float sR[8][4][HH];   // 32 KB: phase-B partials

    const int i = (wv << 6) + lane;
    const _Float16* wp = W4h + ((size_t)b * 32 * TE + i) * 8;
    const float* ua = Uhe + (size_t)jj0 * HH;   // block-uniform -> s_load
    const float* va = Va;                        // uniform

    float a0 = 0.f, a1 = 0.f, a2 = 0.f, a3 = 0.f;

    // 8-way batched reciprocal for one j: sum_{t=0..7} v_t/(1+w_t*u_t)
    //   = (num4a*den4b + num4b*den4a) / (den4a*den4b)
#define OSTEP(ACC, UA, UB)                                                \
    {                                                                     \
        float A0 = fmaf(w0, (UA).x, 1.f);                                 \
        float A1 = fmaf(w1, (UA).y, 1.f);                                 \
        float A2 = fmaf(w2, (UA).z, 1.f);                                 \
        float A3 = fmaf(w3, (UA).w, 1.f);                                 \
        float A4 = fmaf(w4, (UB).x, 1.f);                                 \
        float A5 = fmaf(w5, (UB).y, 1.f);                                 \
        float A6 = fmaf(w6, (UB).z, 1.f);                                 \
        float A7 = fmaf(w7, (UB).w, 1.f);                                 \
        float dab = A0 * A1, dcd = A2 * A3;                               \
        float def_ = A4 * A5, dgh = A6 * A7;                              \
        float nab = fmaf(v4a.x, A1, v4a.y * A0);                          \
        float ncd = fmaf(v4a.z, A3, v4a.w * A2);                          \
        float nef = fmaf(v4b.x, A5, v4b.y * A4);                          \
        float ngh = fmaf(v4b.z, A7, v4b.w * A6);                          \
        float den4a = dab * dcd,  den4b = def_ * dgh;                     \
        float num4a = fmaf(nab, dcd, ncd * dab);                          \
        float num4b = fmaf(nef, dgh, ngh * def_);                         \
        float num = fmaf(num4a, den4b, num4b * den4a);                    \
        ACC = fmaf(num, RCPF(den4a * den4b), ACC);                        \
    }

    #pragma unroll 2
    for (int q = 0; q < 32; q++) {
        h8 w8 = *(const h8*)(wp + (size_t)q * TE * 8);
        float w0 = (float)w8[0], w1 = (float)w8[1];
        float w2 = (float)w8[2], w3 = (float)w8[3];
        float w4 = (float)w8[4], w5 = (float)w8[5];
        float w6 = (float)w8[6], w7 = (float)w8[7];
        float4 v4a = *(const float4*)(va + 8 * q);       // uniform
        float4 v4b = *(const float4*)(va + 8 * q + 4);
        float4 u0a = *(const float4*)(ua + 8 * q);       // uniform, j0
        float4 u0b = *(const float4*)(ua + 8 * q + 4);
        float4 u1a = *(const float4*)(ua + HH + 8 * q);
        float4 u1b = *(const float4*)(ua + HH + 8 * q + 4);
        float4 u2a = *(const float4*)(ua + 2 * HH + 8 * q);
        float4 u2b = *(const float4*)(ua + 2 * HH + 8 * q + 4);
        float4 u3a = *(const float4*)(ua + 3 * HH + 8 * q);
        float4 u3b = *(const float4*)(ua + 3 * HH + 8 * q + 4);
        OSTEP(a0, u0a, u0b)
        OSTEP(a1, u1a, u1b)
        OSTEP(a2, u2a, u2b)
        OSTEP(a3, u3a, u3b)
    }
#undef OSTEP

    // conflict-free b32 writes (lane-stride 4B), energies in log2 domain
    sP[0][i] = NSC * a0;
    sP[1][i] = NSC * a1;
    sP[2][i] = NSC * a2;
    sP[3][i] = NSC * a3;
    __syncthreads();

    // ---- softmax: wave w in 0..3 handles j0+w ----------------------------
    if (wv < 4) {
        float ev[8];
        float m = -3.0e38f;
        #pragma unroll
        for (int k = 0; k < 8; k++) {
            ev[k] = sP[wv][lane + 64 * k];
            m = fmaxf(m, ev[k]);
        }
        #pragma unroll
        for (int off = 32; off; off >>= 1) m = fmaxf(m, __shfl_xor(m, off, 64));
        float s = 0.f;
        #pragma unroll
        for (int k = 0; k < 8; k++) { ev[k] = EXP2F(ev[k] - m); s += ev[k]; }
        #pragma unroll
        for (int off = 32; off; off >>= 1) s += __shfl_xor(s, off, 64);
        float rs = RCPF(s);
        float* oe = out_e + (size_t)(jj0 + wv) * TE;
        #pragma unroll
        for (int k = 0; k < 8; k++) {
            float p = ev[k] * rs;
            sP[wv][lane + 64 * k] = p;
            oe[lane + 64 * k] = p;
        }
    }
    __syncthreads();

    // ---- Phase B: wave w -> i in [64w, 64w+64), all 4 j, fp16 enc --------
    const int ib = wv << 6;
    const _Float16* eb = enc16 + ((size_t)b * TE + ib) * HH + 4 * lane;
    float4 c0 = {0,0,0,0}, c1 = {0,0,0,0}, c2 = {0,0,0,0}, c3 = {0,0,0,0};
    #pragma unroll 2
    for (int k = 0; k < 64; k++) {
        float p0 = sP[0][ib + k];   // uniform broadcasts
        float p1 = sP[1][ib + k];
        float p2 = sP[2][ib + k];
        float p3 = sP[3][ib + k];
        h4 q16 = *(const h4*)(eb + (size_t)k * HH);
        float qx = (float)q16.x, qy = (float)q16.y;
        float qz = (float)q16.z, qw = (float)q16.w;
        c0.x = fmaf(p0, qx, c0.x); c0.y = fmaf(p0, qy, c0.y);
        c0.z = fmaf(p0, qz, c0.z); c0.w = fmaf(p0, qw, c0.w);
        c1.x = fmaf(p1, qx, c1.x); c1.y = fmaf(p1, qy, c1.y);
        c1.z = fmaf(p1, qz, c1.z); c1.w = fmaf(p1, qw, c1.w);
        c2.x = fmaf(p2, qx, c2.x); c2.y = fmaf(p2, qy, c2.y);
        c2.z = fmaf(p2, qz, c2.z); c2.w = fmaf(p2, qw, c2.w);
        c3.x = fmaf(p3, qx, c3.x); c3.y = fmaf(p3, qy, c3.y);
        c3.z = fmaf(p3, qz, c3.z); c3.w = fmaf(p3, qw, c3.w);
    }
    *(float4*)&sR[wv][0][4 * lane] = c0;
    *(float4*)&sR[wv][1][4 * lane] = c1;
    *(float4*)&sR[wv][2][4 * lane] = c2;
    *(float4*)&sR[wv][3][4 * lane] = c3;
    __syncthreads();

    // ---- final reduce: wave w -> (j = w&3, h-half = w>>2) ----------------
    {
        const int jr = wv & 3;
        const int h2 = (wv >> 2) * 128 + 2 * lane;
        float sx = 0.f, sy = 0.f;
        #pragma unroll
        for (int ww = 0; ww < 8; ww++) {
            float2 t = *(const float2*)&sR[ww][jr][h2];
            sx += t.x; sy += t.y;
        }
        float2 o; o.x = sx; o.y = sy;
        *(float2*)(out_c + (size_t)(jj0 + jr) * HH + h2) = o;
    }
}

extern "C" void kernel_launch(void* const* d_in, const int* in_sizes, int n_in,
                              void* d_out, int out_size, void* d_ws, size_t ws_size,
                              hipStream_t stream) {
    const float* enc = (const float*)d_in[0];
    const float* dec = (const float*)d_in[1];
    const float* Wa  = (const float*)d_in[2];
    const float* Ua  = (const float*)d_in[3];
    const float* Va  = (const float*)d_in[4];

    // workspace layout (fp16 operand caches + fp32 Uhe)
    _Float16* W4h   = (_Float16*)d_ws;                       // B*H*TE fp16 (2 MB)
    _Float16* enc16 = W4h + (size_t)BB * HH * TE;            // B*TE*H fp16 (2 MB)
    float*    Uhe   = (float*)(enc16 + (size_t)BB * TE * HH); // B*TD*H fp32 (2 MB)

    float* out_c = (float*)d_out;                    // [B,TD,H]
    float* out_e = out_c + (size_t)BB * TD * HH;     // [B,TD,TE]

    k_pre<<<448, 256, 0, stream>>>(enc, dec, Wa, Ua, W4h, Uhe, enc16);
    k_attn<<<BB * TD / 4, 512, 0, stream>>>(enc16, W4h, Uhe, Va, out_c, out_e);
}